// Round 3
// baseline (827.268 us; speedup 1.0000x reference)
//
#include <hip/hip_runtime.h>
#include <hip/hip_bf16.h>
#include <stdint.h>

// CompressedLinear: out[M=8192, N=4096] = x[M,K=4096] @ (w8[N,K]*scale[N])^T + bias[N]
// Strategy: split-bf16 (hi/lo) MFMA GEMM; weight int8 -> bf16 exact; scale/bias in epilogue.

#define M_TOT 8192
#define N_TOT 4096
#define K_TOT 4096

#define BM 128
#define BN 128
#define BK 32

typedef uint32_t u32;
typedef __attribute__((ext_vector_type(4))) float f32x4;
typedef __attribute__((ext_vector_type(8))) __bf16 bf16x8;

#define GLOBAL_AS __attribute__((address_space(1)))
#define LDS_AS __attribute__((address_space(3)))
// async global->LDS, 16B per lane, LDS dest = wave-uniform base + lane*16
#define ASYNC_COPY16(gp, lp) \
  __builtin_amdgcn_global_load_lds((GLOBAL_AS void*)(gp), (LDS_AS void*)(lp), 16, 0, 0)

__device__ __forceinline__ uint16_t bf16_rne(float f) {
  u32 u = __builtin_bit_cast(u32, f);
  u32 r = u + 0x7FFFu + ((u >> 16) & 1u);
  return (uint16_t)(r >> 16);
}

// ---- prepass 1: x fp32 -> x_hi bf16, x_lo bf16 (x = hi + lo to ~2^-16 rel) ----
__global__ __launch_bounds__(256) void cvt_x_kernel(const float* __restrict__ x,
                                                    uint16_t* __restrict__ hi,
                                                    uint16_t* __restrict__ lo,
                                                    int n4) {
  int idx = blockIdx.x * blockDim.x + threadIdx.x;
  int stride = gridDim.x * blockDim.x;
  for (int i = idx; i < n4; i += stride) {
    float4 v = reinterpret_cast<const float4*>(x)[i];
    float fv[4] = {v.x, v.y, v.z, v.w};
    uint16_t hh[4], ll[4];
#pragma unroll
    for (int j = 0; j < 4; ++j) {
      uint16_t hb = bf16_rne(fv[j]);
      float hf = __builtin_bit_cast(float, (u32)hb << 16);
      hh[j] = hb;
      ll[j] = bf16_rne(fv[j] - hf);
    }
    uint2 hv, lv;
    hv.x = (u32)hh[0] | ((u32)hh[1] << 16);
    hv.y = (u32)hh[2] | ((u32)hh[3] << 16);
    lv.x = (u32)ll[0] | ((u32)ll[1] << 16);
    lv.y = (u32)ll[2] | ((u32)ll[3] << 16);
    reinterpret_cast<uint2*>(hi)[i] = hv;
    reinterpret_cast<uint2*>(lo)[i] = lv;
  }
}

// ---- prepass 2: w int32 (int8 values) -> bf16, exact ----
__global__ __launch_bounds__(256) void cvt_w_kernel(const int* __restrict__ w,
                                                    uint16_t* __restrict__ wb,
                                                    int n4) {
  int idx = blockIdx.x * blockDim.x + threadIdx.x;
  int stride = gridDim.x * blockDim.x;
  for (int i = idx; i < n4; i += stride) {
    int4 v = reinterpret_cast<const int4*>(w)[i];
    // |w| <= 128: float conversion then truncate-to-bf16 is exact
    uint16_t r0 = (uint16_t)(__builtin_bit_cast(u32, (float)v.x) >> 16);
    uint16_t r1 = (uint16_t)(__builtin_bit_cast(u32, (float)v.y) >> 16);
    uint16_t r2 = (uint16_t)(__builtin_bit_cast(u32, (float)v.z) >> 16);
    uint16_t r3 = (uint16_t)(__builtin_bit_cast(u32, (float)v.w) >> 16);
    uint2 rv;
    rv.x = (u32)r0 | ((u32)r1 << 16);
    rv.y = (u32)r2 | ((u32)r3 << 16);
    reinterpret_cast<uint2*>(wb)[i] = rv;
  }
}

// ---- main GEMM: 128x128 tile, BK=32, 4 waves (2x2, 64x64 each), split-bf16 ----
__global__ __launch_bounds__(256, 2) void gemm_kernel(
    const uint16_t* __restrict__ xhi, const uint16_t* __restrict__ xlo,
    const uint16_t* __restrict__ wb, const float* __restrict__ scale,
    const float* __restrict__ bias, float* __restrict__ out) {
  __shared__ __align__(16) uint16_t sAhi[BM * BK];
  __shared__ __align__(16) uint16_t sAlo[BM * BK];
  __shared__ __align__(16) uint16_t sW[BN * BK];

  const int NBX = N_TOT / BN;              // 32
  const int NWG = (M_TOT / BM) * NBX;      // 2048 (%8 == 0 -> simple swizzle bijective)
  int wg = (int)blockIdx.x;
  wg = (wg & 7) * (NWG >> 3) + (wg >> 3);  // XCD-aware swizzle
  const int by = wg / NBX;
  const int bx = wg % NBX;
  const int m0 = by * BM;
  const int n0 = bx * BN;

  const int tid = (int)threadIdx.x;
  const int lane = tid & 63;
  const int wid = tid >> 6;         // 0..3
  const int wm = (wid >> 1) * 64;   // wave row offset in tile
  const int wn = (wid & 1) * 64;    // wave col offset

  // staging: per wave-issue 1024B = 16 rows x 64B; lane -> row=lane>>2, 16B chunk=lane&3
  const int srow = lane >> 2;
  const int scol = (lane & 3) * 8;  // bf16 elements

  // fragment geometry for 16x16x32: A: row=lane&15, k=(lane>>4)*8+j ; B mirrored on cols
  const int fr = lane & 15;
  const int fk = (lane >> 4) * 8;

  f32x4 acc[4][4] = {};

  for (int ks = 0; ks < K_TOT / BK; ++ks) {
    const int k0 = ks * BK;
    __syncthreads();  // all waves done reading previous tile
#pragma unroll
    for (int i = 0; i < 2; ++i) {
      const int chunk = wid * 2 + i;       // 0..7 (16 rows each)
      const int row = chunk * 16 + srow;   // 0..127
      const size_t ga = (size_t)(m0 + row) * K_TOT + (size_t)(k0 + scol);
      const size_t gw = (size_t)(n0 + row) * K_TOT + (size_t)(k0 + scol);
      ASYNC_COPY16(xhi + ga, &sAhi[chunk * 16 * BK]);
      ASYNC_COPY16(xlo + ga, &sAlo[chunk * 16 * BK]);
      ASYNC_COPY16(wb + gw, &sW[chunk * 16 * BK]);
    }
    __syncthreads();  // vmcnt(0) drained by barrier semantics -> LDS ready

    bf16x8 ah[4], al[4], bf[4];
#pragma unroll
    for (int m = 0; m < 4; ++m) {
      const int r = wm + m * 16 + fr;
      ah[m] = *reinterpret_cast<const bf16x8*>(&sAhi[r * BK + fk]);
      al[m] = *reinterpret_cast<const bf16x8*>(&sAlo[r * BK + fk]);
    }
#pragma unroll
    for (int n = 0; n < 4; ++n) {
      const int c = wn + n * 16 + fr;
      bf[n] = *reinterpret_cast<const bf16x8*>(&sW[c * BK + fk]);
    }
#pragma unroll
    for (int m = 0; m < 4; ++m) {
#pragma unroll
      for (int n = 0; n < 4; ++n) {
        acc[m][n] = __builtin_amdgcn_mfma_f32_16x16x32_bf16(ah[m], bf[n], acc[m][n], 0, 0, 0);
        acc[m][n] = __builtin_amdgcn_mfma_f32_16x16x32_bf16(al[m], bf[n], acc[m][n], 0, 0, 0);
      }
    }
  }

  // epilogue: C/D layout col=lane&15, row=(lane>>4)*4+j (verified m89/m91)
  const int fq = lane >> 4;
#pragma unroll
  for (int n = 0; n < 4; ++n) {
    const int col = n0 + wn + n * 16 + (lane & 15);
    const float sc = scale[col];
    const float bi = bias[col];
#pragma unroll
    for (int m = 0; m < 4; ++m) {
      const int rbase = m0 + wm + m * 16 + fq * 4;
#pragma unroll
      for (int j = 0; j < 4; ++j) {
        out[(size_t)(rbase + j) * N_TOT + col] = acc[m][n][j] * sc + bi;
      }
    }
  }
}

extern "C" void kernel_launch(void* const* d_in, const int* in_sizes, int n_in,
                              void* d_out, int out_size, void* d_ws, size_t ws_size,
                              hipStream_t stream) {
  const float* x = (const float*)d_in[0];
  const int* w8 = (const int*)d_in[1];
  const float* scale = (const float*)d_in[2];
  const float* bias = (const float*)d_in[3];
  float* out = (float*)d_out;

  // workspace layout: x_hi (64 MiB) | x_lo (64 MiB) | w_bf16 (32 MiB) = 168 MB total
  uint16_t* xhi = (uint16_t*)d_ws;
  uint16_t* xlo = xhi + (size_t)M_TOT * K_TOT;
  uint16_t* wbf = xlo + (size_t)M_TOT * K_TOT;

  const int x_n4 = (M_TOT * K_TOT) / 4;  // 8,388,608
  const int w_n4 = (N_TOT * K_TOT) / 4;  // 4,194,304

  cvt_x_kernel<<<2048, 256, 0, stream>>>(x, xhi, xlo, x_n4);
  cvt_w_kernel<<<1024, 256, 0, stream>>>(w8, wbf, w_n4);

  const int nwg = (M_TOT / BM) * (N_TOT / BN);  // 2048
  gemm_kernel<<<nwg, 256, 0, stream>>>(xhi, xlo, wbf, scale, bias, out);
}

// Round 4
// 714.798 us; speedup vs baseline: 1.1573x; 1.1573x over previous
//
#include <hip/hip_runtime.h>
#include <hip/hip_bf16.h>
#include <stdint.h>

// CompressedLinear: out[M=8192,N=4096] = x[M,K] @ (w8[N,K]*scale[N])^T + bias[N]
// Split-bf16 as single GEMM with K_eff=8192: A' = [x_hi | x_lo], W' = [W | W].
// 256^2 8-phase schedule (m201 template): T2 st_16x32 swizzle + T3/T4 counted vmcnt + T5 setprio.

#define M_TOT 8192
#define N_TOT 4096
#define K_TOT 4096
#define KE    8192
#define BM 256
#define BN 256
#define BK 64
#define NT (KE / BK)  // 128 K-tiles

typedef uint32_t u32;
typedef __attribute__((ext_vector_type(4))) float f32x4;
typedef __attribute__((ext_vector_type(8))) __bf16 bf16x8;

#define GLOBAL_AS __attribute__((address_space(1)))
#define LDS_AS __attribute__((address_space(3)))
#define ASYNC16(gp, lp) \
  __builtin_amdgcn_global_load_lds((const GLOBAL_AS void*)(gp), (LDS_AS void*)(lp), 16, 0, 0)

#define FENCE asm volatile("" ::: "memory")
#define BARRIER __builtin_amdgcn_s_barrier()
#define LGKM0                                      \
  do {                                             \
    asm volatile("s_waitcnt lgkmcnt(0)" ::: "memory"); \
    __builtin_amdgcn_sched_barrier(0);             \
  } while (0)
#define MFMA(a, b, c) __builtin_amdgcn_mfma_f32_16x16x32_bf16((a), (b), (c), 0, 0, 0)

__device__ __forceinline__ uint16_t bf16_rne(float f) {
  u32 u = __builtin_bit_cast(u32, f);
  u32 r = u + 0x7FFFu + ((u >> 16) & 1u);
  return (uint16_t)(r >> 16);
}

// ---- prepass 1: x fp32 -> x_hi bf16, x_lo bf16 (x = hi + lo to ~2^-16 rel) ----
__global__ __launch_bounds__(256) void cvt_x_kernel(const float* __restrict__ x,
                                                    uint16_t* __restrict__ hi,
                                                    uint16_t* __restrict__ lo,
                                                    int n4) {
  int idx = blockIdx.x * blockDim.x + threadIdx.x;
  int stride = gridDim.x * blockDim.x;
  for (int i = idx; i < n4; i += stride) {
    float4 v = reinterpret_cast<const float4*>(x)[i];
    float fv[4] = {v.x, v.y, v.z, v.w};
    uint16_t hh[4], ll[4];
#pragma unroll
    for (int j = 0; j < 4; ++j) {
      uint16_t hb = bf16_rne(fv[j]);
      float hf = __builtin_bit_cast(float, (u32)hb << 16);
      hh[j] = hb;
      ll[j] = bf16_rne(fv[j] - hf);
    }
    uint2 hv, lv;
    hv.x = (u32)hh[0] | ((u32)hh[1] << 16);
    hv.y = (u32)hh[2] | ((u32)hh[3] << 16);
    lv.x = (u32)ll[0] | ((u32)ll[1] << 16);
    lv.y = (u32)ll[2] | ((u32)ll[3] << 16);
    reinterpret_cast<uint2*>(hi)[i] = hv;
    reinterpret_cast<uint2*>(lo)[i] = lv;
  }
}

// ---- prepass 2: w int32 (int8 values) -> bf16, exact ----
__global__ __launch_bounds__(256) void cvt_w_kernel(const int* __restrict__ w,
                                                    uint16_t* __restrict__ wb,
                                                    int n4) {
  int idx = blockIdx.x * blockDim.x + threadIdx.x;
  int stride = gridDim.x * blockDim.x;
  for (int i = idx; i < n4; i += stride) {
    int4 v = reinterpret_cast<const int4*>(w)[i];
    uint16_t r0 = (uint16_t)(__builtin_bit_cast(u32, (float)v.x) >> 16);
    uint16_t r1 = (uint16_t)(__builtin_bit_cast(u32, (float)v.y) >> 16);
    uint16_t r2 = (uint16_t)(__builtin_bit_cast(u32, (float)v.z) >> 16);
    uint16_t r3 = (uint16_t)(__builtin_bit_cast(u32, (float)v.w) >> 16);
    uint2 rv;
    rv.x = (u32)r0 | ((u32)r1 << 16);
    rv.y = (u32)r2 | ((u32)r3 << 16);
    reinterpret_cast<uint2*>(wb)[i] = rv;
  }
}

// ---- main GEMM: 256x256 tile, BK=64, 8 waves (2M x 4N), 8-phase, K_eff=8192 ----
// LDS: 2 buf x 4 regions x 16KiB. Region content: 0=B rows[n0,n0+128), 1=A rows[m0,m0+128),
//      2=A rows[m0+128,m0+256), 3=B rows[n0+128,n0+256).
// Region = 16 subtiles of [16 rows][32 cols] bf16 (1024B); st_16x32 swizzle:
//      stored = logical ^ ((logical>>9 & 1) << 5) within each subtile.
__global__ __launch_bounds__(512, 2) void gemm_kernel(
    const uint16_t* __restrict__ xhi, const uint16_t* __restrict__ xlo,
    const uint16_t* __restrict__ wbf, const float* __restrict__ scale,
    const float* __restrict__ bias, float* __restrict__ out) {
  __shared__ __align__(16) uint8_t lds[131072];

  const int NBX = N_TOT / BN;              // 16
  const int NWG = (M_TOT / BM) * NBX;      // 512 (%8==0 -> simple XCD swizzle bijective)
  int wg = (int)blockIdx.x;
  wg = (wg & 7) * (NWG >> 3) + (wg >> 3);
  const int m0 = (wg / NBX) * BM;
  const int n0 = (wg % NBX) * BN;

  const int tid = (int)threadIdx.x;
  const int lane = tid & 63;
  const int wid = tid >> 6;            // 0..7
  const int wm = (wid >> 2) * 128;     // wave row offset {0,128}
  const int wn = (wid & 3) * 64;       // wave col offset {0,64,128,192}

  // staging lane geometry: lane writes stored bytes [lane*16,+16) of a 1024B subtile;
  // logical = stored ^ ((stored>>9)&1)<<5 (involution)
  const int lg = (lane << 4) ^ (lane & 32);
  const int lrow = lg >> 6;            // 0..15 row within subtile
  const int lcolE = (lg & 63) >> 1;    // element col within 32-col subtile (0,8,16,24)

  // fragment read geometry (16x16x32): row=lane&15, k=(lane>>4)*8
  const int fr = lane & 15;
  const int fk = (lane >> 4) * 8;
  const int inner = ((fr * 64) + (fk * 2)) ^ ((fr & 8) << 2);  // swizzled byte within subtile grid
  const int abase = ((1 + (wm >> 7)) << 14) + inner;           // region 1 or 2
  const int bbase = (((wn >> 7) ? 3 : 0) << 14) + inner;       // region 0 or 3
  const int bq = (wn & 64) ? 4 : 0;

// stage region H (16KiB half-tile) of K-tile T: wave stages subtiles 2*wid, 2*wid+1
#define STAGE(H, T)                                                                  \
  do {                                                                               \
    const int _T = (T);                                                              \
    const uint16_t* _src;                                                            \
    int _row0;                                                                       \
    if ((H) == 1 || (H) == 2) {                                                      \
      _src = (_T < 64) ? xhi : xlo;                                                  \
      _row0 = m0 + (((H) == 2) ? 128 : 0);                                           \
    } else {                                                                         \
      _src = wbf;                                                                    \
      _row0 = n0 + (((H) == 3) ? 128 : 0);                                           \
    }                                                                                \
    const int _k0 = (_T & 63) * BK;                                                  \
    const uint16_t* _s = _src + (size_t)(_row0 + (wid << 4) + lrow) * K_TOT + _k0 + lcolE; \
    uint8_t* _l = lds + (((_T) & 1) << 16) + ((H) << 14) + (wid << 11);              \
    ASYNC16(_s, _l);                                                                 \
    ASYNC16(_s + 32, _l + 1024);                                                     \
  } while (0)

#define RDA(m, ks) (*(const bf16x8*)(lds + bufoff + abase + ((((m) * 2) + (ks)) << 10)))
#define RDB(n, ks) (*(const bf16x8*)(lds + bufoff + bbase + (((((n) + bq) * 2) + (ks)) << 10)))

  f32x4 acc[8][4] = {};

  // prologue: stage tile0 (4 regions) + tile1 regions 0-2  (lead = 7 half-tiles)
  STAGE(0, 0); STAGE(1, 0); STAGE(2, 0); STAGE(3, 0);
  asm volatile("s_waitcnt vmcnt(4)" ::: "memory");
  STAGE(0, 1); STAGE(1, 1); STAGE(2, 1);
  asm volatile("s_waitcnt vmcnt(6)" ::: "memory");
  FENCE;
  BARRIER;

  for (int t = 0; t < NT; ++t) {
    const int bufoff = (t & 1) << 16;
    bf16x8 b0[2][2], b1[2][2], aLo[4][2], aHi[4][2];

    // ---- phase 0: ds_read all B (8) + A m0-3 (8); stage region3 of t+1; MFMA (m0-3)x(n0-1)
#pragma unroll
    for (int n = 0; n < 2; ++n) { b0[n][0] = RDB(n, 0); b0[n][1] = RDB(n, 1); }
#pragma unroll
    for (int n = 0; n < 2; ++n) { b1[n][0] = RDB(n + 2, 0); b1[n][1] = RDB(n + 2, 1); }
#pragma unroll
    for (int m = 0; m < 4; ++m) { aLo[m][0] = RDA(m, 0); aLo[m][1] = RDA(m, 1); }
    if (t + 1 < NT) STAGE(3, t + 1);
    FENCE; BARRIER; LGKM0;
    __builtin_amdgcn_s_setprio(1);
#pragma unroll
    for (int m = 0; m < 4; ++m)
#pragma unroll
      for (int n = 0; n < 2; ++n) {
        acc[m][n] = MFMA(aLo[m][0], b0[n][0], acc[m][n]);
        acc[m][n] = MFMA(aLo[m][1], b0[n][1], acc[m][n]);
      }
    __builtin_amdgcn_s_setprio(0);
    FENCE; BARRIER;

    // ---- phase 1: ds_read A m4-7 (8); stage region0 of t+2; MFMA (m0-3)x(n2-3)
#pragma unroll
    for (int m = 0; m < 4; ++m) { aHi[m][0] = RDA(m + 4, 0); aHi[m][1] = RDA(m + 4, 1); }
    if (t + 2 < NT) STAGE(0, t + 2);
    FENCE; BARRIER; LGKM0;
    __builtin_amdgcn_s_setprio(1);
#pragma unroll
    for (int m = 0; m < 4; ++m)
#pragma unroll
      for (int n = 0; n < 2; ++n) {
        acc[m][n + 2] = MFMA(aLo[m][0], b1[n][0], acc[m][n + 2]);
        acc[m][n + 2] = MFMA(aLo[m][1], b1[n][1], acc[m][n + 2]);
      }
    __builtin_amdgcn_s_setprio(0);
    FENCE; BARRIER;

    // ---- phase 2: stage region1 of t+2; MFMA (m4-7)x(n0-1)
    if (t + 2 < NT) STAGE(1, t + 2);
    FENCE; BARRIER; LGKM0;
    __builtin_amdgcn_s_setprio(1);
#pragma unroll
    for (int m = 0; m < 4; ++m)
#pragma unroll
      for (int n = 0; n < 2; ++n) {
        acc[m + 4][n] = MFMA(aHi[m][0], b0[n][0], acc[m + 4][n]);
        acc[m + 4][n] = MFMA(aHi[m][1], b0[n][1], acc[m + 4][n]);
      }
    __builtin_amdgcn_s_setprio(0);
    FENCE; BARRIER;

    // ---- phase 3: stage region2 of t+2; MFMA (m4-7)x(n2-3); boundary counted-vmcnt
    if (t + 2 < NT) STAGE(2, t + 2);
    FENCE; BARRIER; LGKM0;
    __builtin_amdgcn_s_setprio(1);
#pragma unroll
    for (int m = 0; m < 4; ++m)
#pragma unroll
      for (int n = 0; n < 2; ++n) {
        acc[m + 4][n + 2] = MFMA(aHi[m][0], b1[n][0], acc[m + 4][n + 2]);
        acc[m + 4][n + 2] = MFMA(aHi[m][1], b1[n][1], acc[m + 4][n + 2]);
      }
    __builtin_amdgcn_s_setprio(0);
    if (t < NT - 1) {
      if (t == NT - 2) {
        asm volatile("s_waitcnt vmcnt(0)" ::: "memory");
      } else {
        asm volatile("s_waitcnt vmcnt(6)" ::: "memory");
      }
      FENCE; BARRIER;
    }
  }

  // epilogue: C/D layout col=lane&15, row=(lane>>4)*4+j
  const int fq = lane >> 4;
#pragma unroll
  for (int n = 0; n < 4; ++n) {
    const int col = n0 + wn + n * 16 + fr;
    const float sc = scale[col];
    const float bb = bias[col];
#pragma unroll
    for (int m = 0; m < 8; ++m) {
      const int rb = m0 + wm + m * 16 + fq * 4;
#pragma unroll
      for (int j = 0; j < 4; ++j) {
        out[(size_t)(rb + j) * N_TOT + col] = acc[m][n][j] * sc + bb;
      }
    }
  }
#undef STAGE
#undef RDA
#undef RDB
}

extern "C" void kernel_launch(void* const* d_in, const int* in_sizes, int n_in,
                              void* d_out, int out_size, void* d_ws, size_t ws_size,
                              hipStream_t stream) {
  const float* x = (const float*)d_in[0];
  const int* w8 = (const int*)d_in[1];
  const float* scale = (const float*)d_in[2];
  const float* bias = (const float*)d_in[3];
  float* out = (float*)d_out;

  uint16_t* xhi = (uint16_t*)d_ws;
  uint16_t* xlo = xhi + (size_t)M_TOT * K_TOT;
  uint16_t* wbf = xlo + (size_t)M_TOT * K_TOT;

  const int x_n4 = (M_TOT * K_TOT) / 4;
  const int w_n4 = (N_TOT * K_TOT) / 4;

  cvt_x_kernel<<<2048, 256, 0, stream>>>(x, xhi, xlo, x_n4);
  cvt_w_kernel<<<1024, 256, 0, stream>>>(w8, wbf, w_n4);

  const int nwg = (M_TOT / BM) * (N_TOT / BN);  // 512
  gemm_kernel<<<nwg, 512, 0, stream>>>(xhi, xlo, wbf, scale, bias, out);
}